// Round 23
// baseline (184.520 us; speedup 1.0000x reference)
//
#include <hip/hip_runtime.h>
#include <hip/hip_bf16.h>
#include <math.h>

#define NB 4
#define LL 512
#define FF 128
#define CC 64
#define HH 12
#define DQi 32
#define PP 8
#define HD 384
#define HP3 288
#define DIN 1824
#define NROW (NB*LL)
#define YW 2016

typedef __attribute__((ext_vector_type(8))) short bf16x8;
typedef __attribute__((ext_vector_type(4))) float f32x4;

__device__ inline unsigned short f2b(float x){
  unsigned int u = __float_as_uint(x);
  unsigned int r = (u + 0x7FFFu + ((u>>16)&1u)) >> 16;
  return (unsigned short)r;
}
__device__ inline float b2f(unsigned short s){
  return __uint_as_float(((unsigned)s) << 16);
}

#define BAR() do { asm volatile("s_waitcnt lgkmcnt(0)" ::: "memory"); __builtin_amdgcn_s_barrier(); } while(0)

// ---------------- K1: MFMA projection GEMM (bf16 output) ----------------
__global__ __launch_bounds__(256) void k_projm(
  const float* __restrict__ x, const unsigned short* __restrict__ WprojT,
  unsigned short* __restrict__ yraw)
{
  __shared__ unsigned short xb[16*136];
  int bh = blockIdx.x & 1; int row0 = (blockIdx.x >> 1) * 16;
  int t = threadIdx.x; int w = t >> 6; int l = t & 63;
  int l15 = l & 15, lg4 = l >> 4;
  for (int idx = t; idx < 512; idx += 256) {
    int r = idx >> 5, c4 = idx & 31;
    float4 v = ((const float4*)&x[(size_t)(row0+r)*FF])[c4];
    unsigned short* d = &xb[r*136 + c4*4];
    d[0]=f2b(v.x); d[1]=f2b(v.y); d[2]=f2b(v.z); d[3]=f2b(v.w);
  }
  __syncthreads();
  bf16x8 a[4];
  #pragma unroll
  for (int ks=0; ks<4; ++ks) a[ks] = *(const bf16x8*)&xb[l15*136 + ks*32 + lg4*8];
  for (int ct = bh*63 + w; ct < bh*63 + 63; ct += 4) {
    int c0 = ct*16;
    f32x4 acc = (f32x4){0.f,0.f,0.f,0.f};
    #pragma unroll
    for (int ks=0; ks<4; ++ks) {
      bf16x8 b = *(const bf16x8*)&WprojT[(size_t)(c0+l15)*FF + ks*32 + lg4*8];
      acc = __builtin_amdgcn_mfma_f32_16x16x32_bf16(a[ks], b, acc, 0,0,0);
    }
    #pragma unroll
    for (int r=0;r<4;++r)
      yraw[(size_t)(row0 + lg4*4 + r)*YW + c0 + l15] = f2b(acc[r]);
  }
}

// ---------------- K1b: transform locals + pack (kpn folded; bf16 yraw in) ----------------
__global__ __launch_bounds__(256) void k_pack2(
  const unsigned short* __restrict__ yraw, const float* __restrict__ R, const float* __restrict__ coord,
  const float* __restrict__ sc, const float* __restrict__ Wpb,
  unsigned short* __restrict__ Arow, unsigned short* __restrict__ Bvec,
  unsigned short* __restrict__ Vcat, unsigned short* __restrict__ WpbT)
{
  const float C3 = 0.57735026918962576f;
  const float C1C3 = 0.17677669529663687f * C3;
  int row0 = blockIdx.x * 8;
  int t = threadIdx.x;
  __shared__ float pg[3][8][288];
  __shared__ float kpn_sh[8][12];
  for (int idx = t; idx < 2304; idx += 256) {
    int lr = idx / 288; int rem = idx % 288; int which = rem / 96; int m = rem % 96;
    int row = row0 + lr;
    const float* Rl = &R[(size_t)row*9];
    const unsigned short* pl = &yraw[(size_t)row*YW + 1152 + which*288 + m*3];
    float p0 = b2f(pl[0]), p1 = b2f(pl[1]), p2 = b2f(pl[2]);
    pg[which][lr][m*3+0] = Rl[0]*p0 + Rl[1]*p1 + Rl[2]*p2 + coord[(size_t)row*3+0];
    pg[which][lr][m*3+1] = Rl[3]*p0 + Rl[4]*p1 + Rl[5]*p2 + coord[(size_t)row*3+1];
    pg[which][lr][m*3+2] = Rl[6]*p0 + Rl[7]*p1 + Rl[8]*p2 + coord[(size_t)row*3+2];
  }
  __syncthreads();
  for (int idx = t; idx < 96; idx += 256) {
    int lr = idx / 12, h = idx % 12;
    float cof = -log1pf(__expf(sc[h])) * (1.0f/12.0f);
    float ss = 0.f;
    for (int e=0;e<24;++e){ float vv = pg[1][lr][h*24+e]; ss += vv*vv; }
    kpn_sh[lr][h] = cof * C3 * ss;
  }
  __syncthreads();
  for (int idx = t; idx < 8*768; idx += 256) {
    int lr = idx / 768; int rem = idx % 768; int h = rem >> 6; int d = rem & 63;
    int row = row0 + lr;
    float cof = -log1pf(__expf(sc[h])) * (1.0f/12.0f);
    float av, bv;
    if (d < 32) {
      av = b2f(yraw[(size_t)row*YW + h*32 + d]) * C1C3;
      bv = b2f(yraw[(size_t)row*YW + 384 + h*32 + d]);
    } else if (d < 56) {
      int e = d-32;
      av = pg[0][lr][h*24+e] * (-2.0f*cof*C3);
      bv = pg[1][lr][h*24+e];
    } else if (d == 56) { av = 1.0f; bv = kpn_sh[lr][h]; }
    else if (d == 57) {
      av = 1.0f;
      float kv = kpn_sh[lr][h];
      bv = kv - __uint_as_float(((unsigned)f2b(kv))<<16);
    }
    else { av = 0.f; bv = 0.f; }
    Arow[(size_t)row*768 + rem] = f2b(av);
    Bvec[(size_t)row*768 + rem] = f2b(bv);
  }
  int n = row0 >> 9; int j0l = row0 & 511;
  for (int idx = t; idx < 768; idx += 256) {
    int h = idx >> 6, d = idx & 63;
    unsigned short tmp[8];
    for (int lr=0; lr<8; ++lr) {
      unsigned short vv;
      if (d < 32) vv = yraw[(size_t)(row0+lr)*YW + 768 + h*32 + d];
      else if (d < 56) vv = f2b(pg[2][lr][h*24 + (d-32)]);
      else vv = 0;
      tmp[lr] = vv;
    }
    uint4 pk;
    pk.x = (unsigned)tmp[0] | ((unsigned)tmp[1]<<16);
    pk.y = (unsigned)tmp[2] | ((unsigned)tmp[3]<<16);
    pk.z = (unsigned)tmp[4] | ((unsigned)tmp[5]<<16);
    pk.w = (unsigned)tmp[6] | ((unsigned)tmp[7]<<16);
    *(uint4*)&Vcat[(((size_t)n*12 + h)*64 + d)*512 + j0l] = pk;
  }
  if (blockIdx.x == 0) {
    for (int idx = t; idx < 16*64; idx += 256) {
      int h = idx >> 6, c = idx & 63;
      WpbT[idx] = (h < HH) ? f2b(Wpb[c*HH + h] * C3) : (unsigned short)0;
    }
  }
}

// ---------------- K1c: pack weights ----------------
__global__ __launch_bounds__(256) void k_packW(
  const float* __restrict__ Wout, const float* __restrict__ Wm1,
  const float* __restrict__ Wm2, const float* __restrict__ Wm3,
  const float* __restrict__ Wq, const float* __restrict__ Wk, const float* __restrict__ Wv,
  const float* __restrict__ Wqp, const float* __restrict__ Wkp, const float* __restrict__ Wvp,
  unsigned short* __restrict__ WoutT, unsigned short* __restrict__ WmT,
  unsigned short* __restrict__ WprojT)
{
  int b = blockIdx.x; int t = threadIdx.x;
  if (b < 128) {
    for (int k = t; k < DIN; k += 256)
      WoutT[(size_t)b*DIN + k] = f2b(Wout[(size_t)k*128 + b]);
  } else if (b < 256) {
    int c = b - 128;
    #pragma unroll
    for (int s=0;s<3;++s) {
      const float* Wl = (s==0)?Wm1:((s==1)?Wm2:Wm3);
      if (t < 128) WmT[(s*128 + c)*128 + t] = f2b(Wl[(size_t)t*128 + c]);
    }
  } else {
    int col = b - 256;
    const float* Ws; int c; int stride;
    if (col < 384)       { Ws = Wq;  c = col;        stride = 384; }
    else if (col < 768)  { Ws = Wk;  c = col - 384;  stride = 384; }
    else if (col < 1152) { Ws = Wv;  c = col - 768;  stride = 384; }
    else if (col < 1440) { Ws = Wqp; c = col - 1152; stride = 288; }
    else if (col < 1728) { Ws = Wkp; c = col - 1440; stride = 288; }
    else                 { Ws = Wvp; c = col - 1728; stride = 288; }
    if (t < 128) WprojT[(size_t)col*128 + t] = f2b(Ws[(size_t)t*stride + c]);
  }
}

// ---------------- K2: fused attention, XCD-swizzled, all-lane softmax, Bvec reg-prefetch ----------------
#define LGP(i,j,h) ((i)*416 + (j)*13 + (h))
__global__ void __launch_bounds__(512,1) k_attn(
  const float* __restrict__ pf, const unsigned short* __restrict__ Arow,
  const unsigned short* __restrict__ Bvec, const unsigned short* __restrict__ Vcat,
  const unsigned short* __restrict__ WpbT,
  const float* __restrict__ R, const float* __restrict__ coord,
  unsigned short* __restrict__ featb)
{
  extern __shared__ char smem_raw[];
  unsigned short* pftile = (unsigned short*)smem_raw;
  unsigned short* W1 = (unsigned short*)(smem_raw + 81920);
  unsigned short* W2 = (unsigned short*)(smem_raw + 90240);
  float* lgP   = (float*)(smem_raw + 100480);
  float* sden  = lgP;
  float* aggr  = (float*)smem_raw;

  int b = (blockIdx.x & 7) * 32 + (blockIdx.x >> 3);
  int ib = b & 63; int n = b >> 6;
  int i0 = ib * 8;
  int t = threadIdx.x; int w = t >> 6; int l = t & 63;
  int l15 = l & 15, lg4 = l >> 4;

  for (int idx = t; idx < 4640; idx += 512) ((unsigned*)W1)[idx] = 0u;

  if (w >= 4) {
    // ================= LOADER waves =================
    int lw = w - 4;
    bf16x8 aPV[2];
    #pragma unroll
    for (int ks=0; ks<2; ++ks)
      aPV[ks] = *(const bf16x8*)&WpbT[l15*64 + ks*32 + lg4*8];

    float4 rbuf[16];
    #pragma unroll
    for (int pp=0; pp<4; ++pp) {
      int p = 4*lw + pp; int ii = p >> 1; int jloc = (p & 1)*16 + l15;
      const float* src = pf + ((size_t)(n*LL + i0 + ii)*LL + jloc)*CC + lg4*8;
      #pragma unroll
      for (int ks=0; ks<2; ++ks) {
        rbuf[pp*4+ks*2  ] = *(const float4*)(src + ks*32);
        rbuf[pp*4+ks*2+1] = *(const float4*)(src + ks*32 + 4);
      }
    }
    #pragma unroll
    for (int pp=0; pp<4; ++pp) {
      int p = 4*lw + pp; int ii = p >> 1; int jloc = (p & 1)*16 + l15;
      f32x4 cpv = (f32x4){0.f,0.f,0.f,0.f};
      #pragma unroll
      for (int ks=0; ks<2; ++ks) {
        float4 va = rbuf[pp*4+ks*2], vb = rbuf[pp*4+ks*2+1];
        bf16x8 bb;
        bb[0]=(short)f2b(va.x); bb[1]=(short)f2b(va.y); bb[2]=(short)f2b(va.z); bb[3]=(short)f2b(va.w);
        bb[4]=(short)f2b(vb.x); bb[5]=(short)f2b(vb.y); bb[6]=(short)f2b(vb.z); bb[7]=(short)f2b(vb.w);
        cpv = __builtin_amdgcn_mfma_f32_16x16x32_bf16(aPV[ks], bb, cpv, 0,0,0);
        int cbase = ks*32 + lg4*8;
        #pragma unroll
        for (int e=0;e<8;++e) pftile[ii*2560 + (cbase+e)*40 + jloc] = (unsigned short)bb[e];
      }
      #pragma unroll
      for (int r=0;r<4;++r) { int h2 = lg4*4 + r; if (h2 < HH) lgP[LGP(ii, jloc, h2)] = cpv[r]; }
    }
    BAR();
    for (int jt = 0; jt < 16; ++jt) {
      if (jt < 15) {
        int j0s = (jt+1)*32;
        #pragma unroll
        for (int pp=0; pp<4; ++pp) {
          int p = 4*lw + pp; int ii = p >> 1; int jloc = (p & 1)*16 + l15;
          const float* src = pf + ((size_t)(n*LL + i0 + ii)*LL + (j0s + jloc))*CC + lg4*8;
          #pragma unroll
          for (int ks=0; ks<2; ++ks) {
            rbuf[pp*4+ks*2  ] = *(const float4*)(src + ks*32);
            rbuf[pp*4+ks*2+1] = *(const float4*)(src + ks*32 + 4);
          }
        }
      }
      BAR();                               // b1
      if (jt < 15) {
        int buf = (jt+1)&1;
        unsigned short* pft = pftile + buf*20480;
        float* lgPb = lgP + buf*3328;
        #pragma unroll
        for (int pp=0; pp<4; ++pp) {
          int p = 4*lw + pp; int ii = p >> 1; int jloc = (p & 1)*16 + l15;
          f32x4 cpv = (f32x4){0.f,0.f,0.f,0.f};
          #pragma unroll
          for (int ks=0; ks<2; ++ks) {
            float4 va = rbuf[pp*4+ks*2], vb = rbuf[pp*4+ks*2+1];
            bf16x8 bb;
            bb[0]=(short)f2b(va.x); bb[1]=(short)f2b(va.y); bb[2]=(short)f2b(va.z); bb[3]=(short)f2b(va.w);
            bb[4]=(short)f2b(vb.x); bb[5]=(short)f2b(vb.y); bb[6]=(short)f2b(vb.z); bb[7]=(short)f2b(vb.w);
            cpv = __builtin_amdgcn_mfma_f32_16x16x32_bf16(aPV[ks], bb, cpv, 0,0,0);
            int cbase = ks*32 + lg4*8;
            #pragma unroll
            for (int e=0;e<8;++e) pft[ii*2560 + (cbase+e)*40 + jloc] = (unsigned short)bb[e];
          }
          #pragma unroll
          for (int r=0;r<4;++r) { int h2 = lg4*4 + r; if (h2 < HH) lgPb[LGP(ii, jloc, h2)] = cpv[r]; }
        }
      }
      BAR();                               // b2
    }
    BAR();                                 // B_e1
  } else {
    // ================= COMPUTE waves =================
    bf16x8 zz;
    #pragma unroll
    for (int e=0;e<8;++e) zz[e] = 0;
    bf16x8 aAB[3][2];
    #pragma unroll
    for (int hh=0; hh<3; ++hh) {
      int h = 3*w + hh;
      #pragma unroll
      for (int ks=0; ks<2; ++ks)
        aAB[hh][ks] = (l15 < 8) ? *(const bf16x8*)&Arow[(size_t)(n*LL + i0 + l15)*768 + h*64 + ks*32 + lg4*8] : zz;
    }
    f32x4 cNV[3][4]; f32x4 cP[2][4];
    #pragma unroll
    for (int a=0;a<3;++a)
      #pragma unroll
      for (int nt=0;nt<4;++nt) cNV[a][nt] = (f32x4){0.f,0.f,0.f,0.f};
    #pragma unroll
    for (int a=0;a<2;++a)
      #pragma unroll
      for (int nt=0;nt<4;++nt) cP[a][nt] = (f32x4){0.f,0.f,0.f,0.f};
    float s_acc[3][4];
    #pragma unroll
    for (int a=0;a<3;++a)
      #pragma unroll
      for (int r=0;r<4;++r) s_acc[a][r] = 0.f;

    int jh2 = (lg4 >= 2);
    int ig  = (lg4 & 1) * 4;

    // Bvec register prefetch (consumed in phase L, refilled for jt+1 right after)
    bf16x8 bpre[3][2][2];
    #pragma unroll
    for (int hh=0; hh<3; ++hh) {
      int h = 3*w + hh;
      #pragma unroll
      for (int ks=0; ks<2; ++ks) {
        bpre[hh][ks][0] = *(const bf16x8*)&Bvec[(size_t)(n*LL + l15)*768 + h*64 + ks*32 + lg4*8];
        bpre[hh][ks][1] = *(const bf16x8*)&Bvec[(size_t)(n*LL + 16 + l15)*768 + h*64 + ks*32 + lg4*8];
      }
    }

    BAR();
    for (int jt = 0; jt < 16; ++jt) {
      int j0 = jt*32; int cur = jt & 1;
      unsigned short* pft = pftile + cur*20480;
      float* lgPb = lgP + cur*3328;
      f32x4 cL[3][2];
      #pragma unroll
      for (int hh=0; hh<3; ++hh) {
        cL[hh][0] = (f32x4){0.f,0.f,0.f,0.f};
        cL[hh][1] = (f32x4){0.f,0.f,0.f,0.f};
        #pragma unroll
        for (int ks=0; ks<2; ++ks) {
          cL[hh][0] = __builtin_amdgcn_mfma_f32_16x16x32_bf16(aAB[hh][ks], bpre[hh][ks][0], cL[hh][0], 0,0,0);
          cL[hh][1] = __builtin_amdgcn_mfma_f32_16x16x32_bf16(aAB[hh][ks], bpre[hh][ks][1], cL[hh][1], 0,0,0);
        }
      }
      // refill bpre for jt+1 (loads fly across SM + b1 + A + b2)
      if (jt < 15) {
        int j0n = (jt+1)*32;
        #pragma unroll
        for (int hh=0; hh<3; ++hh) {
          int h = 3*w + hh;
          #pragma unroll
          for (int ks=0; ks<2; ++ks) {
            bpre[hh][ks][0] = *(const bf16x8*)&Bvec[(size_t)(n*LL + j0n + l15)*768 + h*64 + ks*32 + lg4*8];
            bpre[hh][ks][1] = *(const bf16x8*)&Bvec[(size_t)(n*LL + j0n + 16 + l15)*768 + h*64 + ks*32 + lg4*8];
          }
        }
      }
      // ---- SM: all 64 lanes ----
      #pragma unroll
      for (int hh=0; hh<3; ++hh) {
        int h = 3*w + hh;
        #pragma unroll
        for (int r=0;r<4;++r) {
          float other = __shfl_xor(cL[hh][1][r], 32);
          float mine  = (lg4 < 2) ? cL[hh][0][r] : other;
          int i = ig + r;
          int j = jh2*16 + l15;
          float lv = mine + lgPb[LGP(i, j, h)];
          float e = __expf(lv);
          s_acc[hh][r] += e;
          unsigned short eb = f2b(e);
          W1[(h*8 + i)*40 + j] = eb;
          W2[(i*16 + h)*40 + j] = eb;
        }
      }
      BAR();                               // b1
      #pragma unroll
      for (int hh=0; hh<3; ++hh) {
        int h = 3*w + hh;
        bf16x8 aW = *(const bf16x8*)&W1[(h*8 + l15)*40 + lg4*8];
        #pragma unroll
        for (int nt=0; nt<4; ++nt) {
          bf16x8 bV = *(const bf16x8*)&Vcat[(((size_t)n*12 + h)*64 + nt*16 + l15)*512 + j0 + lg4*8];
          cNV[hh][nt] = __builtin_amdgcn_mfma_f32_16x16x32_bf16(aW, bV, cNV[hh][nt], 0,0,0);
        }
      }
      #pragma unroll
      for (int it=0; it<2; ++it) {
        int ii = 2*w + it;
        bf16x8 aW2 = *(const bf16x8*)&W2[(ii*16 + l15)*40 + lg4*8];
        #pragma unroll
        for (int nt=0; nt<4; ++nt) {
          bf16x8 bP = *(const bf16x8*)&pft[ii*2560 + (nt*16 + l15)*40 + lg4*8];
          cP[it][nt] = __builtin_amdgcn_mfma_f32_16x16x32_bf16(aW2, bP, cP[it][nt], 0,0,0);
        }
      }
      BAR();                               // b2
    }
    // ---- epilogue: s reduction ----
    #pragma unroll
    for (int hh=0; hh<3; ++hh) {
      int h = 3*w + hh;
      #pragma unroll
      for (int r=0;r<4;++r) {
        float val = s_acc[hh][r];
        #pragma unroll
        for (int o=1;o<16;o<<=1) val += __shfl_xor(val, o);
        val += __shfl_xor(val, 32);
        if (lg4 < 2 && l15 == 0) sden[(lg4*4 + r)*12 + h] = 1.0f / val;
      }
    }
    BAR();                                 // B_e1
    #pragma unroll
    for (int it=0; it<2; ++it) {
      int ii = 2*w + it;
      size_t fb = (size_t)(n*LL + i0 + ii)*DIN;
      #pragma unroll
      for (int nt=0; nt<4; ++nt)
        #pragma unroll
        for (int r=0;r<4;++r) {
          int h2 = lg4*4 + r;
          if (h2 < HH) featb[fb + h2*64 + nt*16 + l15] = f2b(cP[it][nt][r] * sden[ii*12 + h2]);
        }
    }
    if (lg4 < 2) {
      #pragma unroll
      for (int hh=0; hh<3; ++hh) {
        int h = 3*w + hh;
        #pragma unroll
        for (int r=0;r<4;++r) {
          int i = lg4*4 + r;
          float sd = sden[i*12 + h];
          size_t fb = (size_t)(n*LL + i0 + i)*DIN;
          #pragma unroll
          for (int nt=0; nt<2; ++nt)
            featb[fb + 768 + h*32 + nt*16 + l15] = f2b(cNV[hh][nt][r] * sd);
          #pragma unroll
          for (int nt=2; nt<4; ++nt) {
            int d = nt*16 + l15 - 32;
            if (d < 24) aggr[(i*12 + h)*24 + d] = cNV[hh][nt][r] * sd;
          }
        }
      }
    }
  }
  BAR();                                   // B_e2
  for (int idx = t; idx < 768; idx += 512) {
    int i = idx / 96; int rem = idx % 96; int h = rem >> 3; int p = rem & 7;
    int row = n*LL + i0 + i;
    const float* Rl = &R[(size_t)row*9];
    float X0 = aggr[(i*12 + h)*24 + p*3 + 0] - coord[(size_t)row*3 + 0];
    float X1 = aggr[(i*12 + h)*24 + p*3 + 1] - coord[(size_t)row*3 + 1];
    float X2 = aggr[(i*12 + h)*24 + p*3 + 2] - coord[(size_t)row*3 + 2];
    float p0 = Rl[0]*X0 + Rl[3]*X1 + Rl[6]*X2;
    float p1 = Rl[1]*X0 + Rl[4]*X1 + Rl[7]*X2;
    float p2 = Rl[2]*X0 + Rl[5]*X1 + Rl[8]*X2;
    float dist = sqrtf(p0*p0 + p1*p1 + p2*p2);
    float inv = 1.0f / (dist + 1e-4f);
    size_t fb = (size_t)row * DIN;
    int m = h*8 + p;
    featb[fb + 1152 + m*3 + 0] = f2b(p0);
    featb[fb + 1152 + m*3 + 1] = f2b(p1);
    featb[fb + 1152 + m*3 + 2] = f2b(p2);
    featb[fb + 1440 + m] = f2b(dist);
    featb[fb + 1536 + m*3 + 0] = f2b(p0*inv);
    featb[fb + 1536 + m*3 + 1] = f2b(p1*inv);
    featb[fb + 1536 + m*3 + 2] = f2b(p2*inv);
  }
}

// ---------------- K4: fused outproj + LN1 + MLP + LN2 (4-acc ILP) ----------------
__global__ __launch_bounds__(256) void k_head(
  const unsigned short* __restrict__ featb, const float* __restrict__ x,
  const unsigned short* __restrict__ WoutT, const float* __restrict__ bout,
  const float* __restrict__ g1, const float* __restrict__ b1,
  const unsigned short* __restrict__ WmT,
  const float* __restrict__ bm1, const float* __restrict__ bm2, const float* __restrict__ bm3,
  const float* __restrict__ g2, const float* __restrict__ b2,
  float* __restrict__ out)
{
  __shared__ float ybuf[8*128];
  __shared__ float x1f[8*128];
  __shared__ unsigned short x1b[8*136];
  __shared__ unsigned short hbA[8*136];
  __shared__ unsigned short hbB[8*136];
  int row0 = blockIdx.x * 8;
  int t = threadIdx.x; int w = t >> 6; int l = t & 63;
  int l15 = l & 15, lg4 = l >> 4;

  f32x4 acc0a = (f32x4){0.f,0.f,0.f,0.f}, acc1a = (f32x4){0.f,0.f,0.f,0.f};
  f32x4 acc0b = (f32x4){0.f,0.f,0.f,0.f}, acc1b = (f32x4){0.f,0.f,0.f,0.f};
  const unsigned short* ap  = featb + (size_t)(row0 + (l15 & 7))*DIN + lg4*8;
  const unsigned short* bp0 = WoutT + (size_t)(w*32 + l15)*DIN + lg4*8;
  const unsigned short* bp1 = bp0 + 16*DIN;
  for (int ks = 0; ks < 28; ++ks) {
    bf16x8 aA  = *(const bf16x8*)(ap  + ks*32);
    bf16x8 aB  = *(const bf16x8*)(ap  + (28+ks)*32);
    bf16x8 b0A = *(const bf16x8*)(bp0 + ks*32);
    bf16x8 b0B = *(const bf16x8*)(bp0 + (28+ks)*32);
    bf16x8 b1A = *(const bf16x8*)(bp1 + ks*32);
    bf16x8 b1B = *(const bf16x8*)(bp1 + (28+ks)*32);
    acc0a = __builtin_amdgcn_mfma_f32_16x16x32_bf16(aA, b0A, acc0a, 0,0,0);
    acc0b = __builtin_amdgcn_mfma_f32_16x16x32_bf16(aB, b0B, acc0b, 0,0,0);
    acc1a = __builtin_amdgcn_mfma_f32_16x16x32_bf16(aA, b1A, acc1a, 0,0,0);
    acc1b = __builtin_amdgcn_mfma_f32_16x16x32_bf16(aB, b1B, acc1b, 0,0,0);
  }
  {
    bf16x8 aA  = *(const bf16x8*)(ap  + 56*32);
    bf16x8 b0A = *(const bf16x8*)(bp0 + 56*32);
    bf16x8 b1A = *(const bf16x8*)(bp1 + 56*32);
    acc0a = __builtin_amdgcn_mfma_f32_16x16x32_bf16(aA, b0A, acc0a, 0,0,0);
    acc1a = __builtin_amdgcn_mfma_f32_16x16x32_bf16(aA, b1A, acc1a, 0,0,0);
  }
  f32x4 acc0, acc1;
  #pragma unroll
  for (int r=0;r<4;++r) { acc0[r] = acc0a[r] + acc0b[r]; acc1[r] = acc1a[r] + acc1b[r]; }
  #pragma unroll
  for (int r=0;r<4;++r) {
    int m = lg4*4 + r;
    if (m < 8) {
      ybuf[m*128 + w*32 + l15]      = acc0[r];
      ybuf[m*128 + w*32 + 16 + l15] = acc1[r];
    }
  }
  __syncthreads();

  int row = t >> 5, j = t & 31; int grow = row0 + row;
  {
    float y[4];
    #pragma unroll
    for (int c4=0;c4<4;++c4) {
      int c = j + c4*32;
      y[c4] = ybuf[row*128 + c] + x[(size_t)grow*128 + c] + bout[c];
    }
    float sum = y[0]+y[1]+y[2]+y[3];
    #pragma unroll
    for (int o=1;o<32;o<<=1) sum += __shfl_xor(sum, o);
    float mean = sum * (1.0f/128.0f);
    float vs = 0.f;
    #pragma unroll
    for (int c4=0;c4<4;++c4){ y[c4] -= mean; vs += y[c4]*y[c4]; }
    #pragma unroll
    for (int o=1;o<32;o<<=1) vs += __shfl_xor(vs, o);
    float rstd = rsqrtf(vs*(1.0f/128.0f) + 1e-5f);
    #pragma unroll
    for (int c4=0;c4<4;++c4) {
      int c = j + c4*32;
      float xv = y[c4]*rstd*g1[c] + b1[c];
      x1f[row*128 + c] = xv;
      x1b[row*136 + c] = f2b(xv);
    }
  }
  __syncthreads();

  #pragma unroll
  for (int s=0; s<3; ++s) {
    const unsigned short* Ab = (s==0)? x1b : ((s==1)? hbA : hbB);
    const float* bm = (s==0)? bm1 : ((s==1)? bm2 : bm3);
    const unsigned short* Wl = WmT + s*16384;
    f32x4 a0 = (f32x4){0.f,0.f,0.f,0.f}, a1 = (f32x4){0.f,0.f,0.f,0.f};
    #pragma unroll
    for (int ks=0; ks<4; ++ks) {
      bf16x8 a = *(const bf16x8*)&Ab[(l15 & 7)*136 + ks*32 + lg4*8];
      bf16x8 b0 = *(const bf16x8*)&Wl[(size_t)(w*32 + l15)*128 + ks*32 + lg4*8];
      bf16x8 b1v = *(const bf16x8*)&Wl[(size_t)(w*32 + 16 + l15)*128 + ks*32 + lg4*8];
      a0 = __builtin_amdgcn_mfma_f32_16x16x32_bf16(a, b0, a0, 0,0,0);
      a1 = __builtin_amdgcn_mfma_f32_16x16x32_bf16(a, b1v, a1, 0,0,0);
    }
    unsigned short* Nb = (s==0)? hbA : hbB;
    #pragma unroll
    for (int r=0;r<4;++r) {
      int m = lg4*4 + r;
      if (m < 8) {
        int c0 = w*32 + l15, c1 = w*32 + 16 + l15;
        float y0 = a0[r] + bm[c0];
        float y1 = a1[r] + bm[c1];
        if (s < 2) {
          Nb[m*136 + c0] = f2b(fmaxf(y0, 0.f));
          Nb[m*136 + c1] = f2b(fmaxf(y1, 0.f));
        } else {
          ybuf[m*128 + c0] = y0;
          ybuf[m*128 + c1] = y1;
        }
      }
    }
    __syncthreads();
  }

  {
    float y[4];
    #pragma unroll
    for (int c4=0;c4<4;++c4) {
      int c = j + c4*32;
      y[c4] = x1f[row*128 + c] + ybuf[row*128 + c];
    }
    float sum = y[0]+y[1]+y[2]+y[3];
    #pragma unroll
    for (int o=1;o<32;o<<=1) sum += __shfl_xor(sum, o);
    float mean = sum * (1.0f/128.0f);
    float vs = 0.f;
    #pragma unroll
    for (int c4=0;c4<4;++c4){ y[c4] -= mean; vs += y[c4]*y[c4]; }
    #pragma unroll
    for (int o=1;o<32;o<<=1) vs += __shfl_xor(vs, o);
    float rstd = rsqrtf(vs*(1.0f/128.0f) + 1e-5f);
    #pragma unroll
    for (int c4=0;c4<4;++c4) {
      int c = j + c4*32;
      out[(size_t)grow*128 + c] = y[c4]*rstd*g2[c] + b2[c];
    }
  }
}

extern "C" void kernel_launch(void* const* d_in, const int* in_sizes, int n_in,
                              void* d_out, int out_size, void* d_ws, size_t ws_size,
                              hipStream_t stream) {
  const float* R     = (const float*)d_in[0];
  const float* coord = (const float*)d_in[1];
  const float* x     = (const float*)d_in[2];
  const float* pf    = (const float*)d_in[3];
  const float* Wq    = (const float*)d_in[5];
  const float* Wk    = (const float*)d_in[6];
  const float* Wv    = (const float*)d_in[7];
  const float* Wpb   = (const float*)d_in[8];
  const float* sc    = (const float*)d_in[9];
  const float* Wqp   = (const float*)d_in[10];
  const float* Wkp   = (const float*)d_in[11];
  const float* Wvp   = (const float*)d_in[12];
  const float* Wout  = (const float*)d_in[13];
  const float* bout  = (const float*)d_in[14];
  const float* Wm1   = (const float*)d_in[15];
  const float* bm1   = (const float*)d_in[16];
  const float* Wm2   = (const float*)d_in[17];
  const float* bm2   = (const float*)d_in[18];
  const float* Wm3   = (const float*)d_in[19];
  const float* bm3   = (const float*)d_in[20];
  const float* g1    = (const float*)d_in[21];
  const float* b1    = (const float*)d_in[22];
  const float* g2    = (const float*)d_in[23];
  const float* b2    = (const float*)d_in[24];

  float* ws = (float*)d_ws;
  unsigned short* yraw = (unsigned short*)ws;          // 2048*2016 bf16
  float* after    = ws + 2064384;
  unsigned short* Arow = (unsigned short*)after;
  unsigned short* Bvec = (unsigned short*)(after + 786432);
  unsigned short* Vcat = (unsigned short*)(after + 1572864);
  unsigned short* WpbT = (unsigned short*)(after + 2359296);
  unsigned short* featb = (unsigned short*)(after + 2384384);
  unsigned short* WoutT = (unsigned short*)(after + 2384384 + 1867776);
  unsigned short* WmT   = (unsigned short*)(after + 2384384 + 1867776 + 116736);
  unsigned short* WprojT= (unsigned short*)(after + 2384384 + 1867776 + 116736 + 24576);
  float* out      = (float*)d_out;

  k_packW<<<dim3(2272), dim3(256), 0, stream>>>(Wout,Wm1,Wm2,Wm3,Wq,Wk,Wv,Wqp,Wkp,Wvp,WoutT,WmT,WprojT);
  k_projm<<<dim3(256), dim3(256), 0, stream>>>(x, WprojT, yraw);
  k_pack2<<<dim3(NROW/8), dim3(256), 0, stream>>>(yraw,R,coord,sc,Wpb,Arow,Bvec,Vcat,WpbT);
  hipFuncSetAttribute((const void*)k_attn, hipFuncAttributeMaxDynamicSharedMemorySize, 127104);
  k_attn<<<dim3(256), dim3(512), 127104, stream>>>(pf, Arow, Bvec, Vcat, WpbT, R, coord, featb);
  k_head<<<dim3(NROW/8), dim3(256), 0, stream>>>(featb, x, WoutT, bout, g1, b1, WmT, bm1, bm2, bm3, g2, b2, out);
}

// Round 24
// 162.237 us; speedup vs baseline: 1.1374x; 1.1374x over previous
//
#include <hip/hip_runtime.h>
#include <hip/hip_bf16.h>
#include <math.h>

#define NB 4
#define LL 512
#define FF 128
#define CC 64
#define HH 12
#define DQi 32
#define PP 8
#define HD 384
#define HP3 288
#define DIN 1824
#define NROW (NB*LL)
#define YW 2016

typedef __attribute__((ext_vector_type(8))) short bf16x8;
typedef __attribute__((ext_vector_type(4))) float f32x4;

__device__ inline unsigned short f2b(float x){
  unsigned int u = __float_as_uint(x);
  unsigned int r = (u + 0x7FFFu + ((u>>16)&1u)) >> 16;
  return (unsigned short)r;
}
__device__ inline float b2f(unsigned short s){
  return __uint_as_float(((unsigned)s) << 16);
}

#define BAR() do { asm volatile("s_waitcnt lgkmcnt(0)" ::: "memory"); __builtin_amdgcn_s_barrier(); } while(0)

// ---------------- K1: MFMA projection GEMM (bf16 output) ----------------
__global__ __launch_bounds__(256) void k_projm(
  const float* __restrict__ x, const unsigned short* __restrict__ WprojT,
  unsigned short* __restrict__ yraw)
{
  __shared__ unsigned short xb[16*136];
  int bh = blockIdx.x & 1; int row0 = (blockIdx.x >> 1) * 16;
  int t = threadIdx.x; int w = t >> 6; int l = t & 63;
  int l15 = l & 15, lg4 = l >> 4;
  for (int idx = t; idx < 512; idx += 256) {
    int r = idx >> 5, c4 = idx & 31;
    float4 v = ((const float4*)&x[(size_t)(row0+r)*FF])[c4];
    unsigned short* d = &xb[r*136 + c4*4];
    d[0]=f2b(v.x); d[1]=f2b(v.y); d[2]=f2b(v.z); d[3]=f2b(v.w);
  }
  __syncthreads();
  bf16x8 a[4];
  #pragma unroll
  for (int ks=0; ks<4; ++ks) a[ks] = *(const bf16x8*)&xb[l15*136 + ks*32 + lg4*8];
  for (int ct = bh*63 + w; ct < bh*63 + 63; ct += 4) {
    int c0 = ct*16;
    f32x4 acc = (f32x4){0.f,0.f,0.f,0.f};
    #pragma unroll
    for (int ks=0; ks<4; ++ks) {
      bf16x8 b = *(const bf16x8*)&WprojT[(size_t)(c0+l15)*FF + ks*32 + lg4*8];
      acc = __builtin_amdgcn_mfma_f32_16x16x32_bf16(a[ks], b, acc, 0,0,0);
    }
    #pragma unroll
    for (int r=0;r<4;++r)
      yraw[(size_t)(row0 + lg4*4 + r)*YW + c0 + l15] = f2b(acc[r]);
  }
}

// ---------------- K1b: transform locals + pack (kpn folded; bf16 yraw in) ----------------
__global__ __launch_bounds__(256) void k_pack2(
  const unsigned short* __restrict__ yraw, const float* __restrict__ R, const float* __restrict__ coord,
  const float* __restrict__ sc, const float* __restrict__ Wpb,
  unsigned short* __restrict__ Arow, unsigned short* __restrict__ Bvec,
  unsigned short* __restrict__ Vcat, unsigned short* __restrict__ WpbT)
{
  const float C3 = 0.57735026918962576f;
  const float C1C3 = 0.17677669529663687f * C3;
  int row0 = blockIdx.x * 8;
  int t = threadIdx.x;
  __shared__ float pg[3][8][288];
  __shared__ float kpn_sh[8][12];
  for (int idx = t; idx < 2304; idx += 256) {
    int lr = idx / 288; int rem = idx % 288; int which = rem / 96; int m = rem % 96;
    int row = row0 + lr;
    const float* Rl = &R[(size_t)row*9];
    const unsigned short* pl = &yraw[(size_t)row*YW + 1152 + which*288 + m*3];
    float p0 = b2f(pl[0]), p1 = b2f(pl[1]), p2 = b2f(pl[2]);
    pg[which][lr][m*3+0] = Rl[0]*p0 + Rl[1]*p1 + Rl[2]*p2 + coord[(size_t)row*3+0];
    pg[which][lr][m*3+1] = Rl[3]*p0 + Rl[4]*p1 + Rl[5]*p2 + coord[(size_t)row*3+1];
    pg[which][lr][m*3+2] = Rl[6]*p0 + Rl[7]*p1 + Rl[8]*p2 + coord[(size_t)row*3+2];
  }
  __syncthreads();
  for (int idx = t; idx < 96; idx += 256) {
    int lr = idx / 12, h = idx % 12;
    float cof = -log1pf(__expf(sc[h])) * (1.0f/12.0f);
    float ss = 0.f;
    for (int e=0;e<24;++e){ float vv = pg[1][lr][h*24+e]; ss += vv*vv; }
    kpn_sh[lr][h] = cof * C3 * ss;
  }
  __syncthreads();
  for (int idx = t; idx < 8*768; idx += 256) {
    int lr = idx / 768; int rem = idx % 768; int h = rem >> 6; int d = rem & 63;
    int row = row0 + lr;
    float cof = -log1pf(__expf(sc[h])) * (1.0f/12.0f);
    float av, bv;
    if (d < 32) {
      av = b2f(yraw[(size_t)row*YW + h*32 + d]) * C1C3;
      bv = b2f(yraw[(size_t)row*YW + 384 + h*32 + d]);
    } else if (d < 56) {
      int e = d-32;
      av = pg[0][lr][h*24+e] * (-2.0f*cof*C3);
      bv = pg[1][lr][h*24+e];
    } else if (d == 56) { av = 1.0f; bv = kpn_sh[lr][h]; }
    else if (d == 57) {
      av = 1.0f;
      float kv = kpn_sh[lr][h];
      bv = kv - __uint_as_float(((unsigned)f2b(kv))<<16);
    }
    else { av = 0.f; bv = 0.f; }
    Arow[(size_t)row*768 + rem] = f2b(av);
    Bvec[(size_t)row*768 + rem] = f2b(bv);
  }
  int n = row0 >> 9; int j0l = row0 & 511;
  for (int idx = t; idx < 768; idx += 256) {
    int h = idx >> 6, d = idx & 63;
    unsigned short tmp[8];
    for (int lr=0; lr<8; ++lr) {
      unsigned short vv;
      if (d < 32) vv = yraw[(size_t)(row0+lr)*YW + 768 + h*32 + d];
      else if (d < 56) vv = f2b(pg[2][lr][h*24 + (d-32)]);
      else vv = 0;
      tmp[lr] = vv;
    }
    uint4 pk;
    pk.x = (unsigned)tmp[0] | ((unsigned)tmp[1]<<16);
    pk.y = (unsigned)tmp[2] | ((unsigned)tmp[3]<<16);
    pk.z = (unsigned)tmp[4] | ((unsigned)tmp[5]<<16);
    pk.w = (unsigned)tmp[6] | ((unsigned)tmp[7]<<16);
    *(uint4*)&Vcat[(((size_t)n*12 + h)*64 + d)*512 + j0l] = pk;
  }
  if (blockIdx.x == 0) {
    for (int idx = t; idx < 16*64; idx += 256) {
      int h = idx >> 6, c = idx & 63;
      WpbT[idx] = (h < HH) ? f2b(Wpb[c*HH + h] * C3) : (unsigned short)0;
    }
  }
}

// ---------------- K1c: pack weights ----------------
__global__ __launch_bounds__(256) void k_packW(
  const float* __restrict__ Wout, const float* __restrict__ Wm1,
  const float* __restrict__ Wm2, const float* __restrict__ Wm3,
  const float* __restrict__ Wq, const float* __restrict__ Wk, const float* __restrict__ Wv,
  const float* __restrict__ Wqp, const float* __restrict__ Wkp, const float* __restrict__ Wvp,
  unsigned short* __restrict__ WoutT, unsigned short* __restrict__ WmT,
  unsigned short* __restrict__ WprojT)
{
  int b = blockIdx.x; int t = threadIdx.x;
  if (b < 128) {
    for (int k = t; k < DIN; k += 256)
      WoutT[(size_t)b*DIN + k] = f2b(Wout[(size_t)k*128 + b]);
  } else if (b < 256) {
    int c = b - 128;
    #pragma unroll
    for (int s=0;s<3;++s) {
      const float* Wl = (s==0)?Wm1:((s==1)?Wm2:Wm3);
      if (t < 128) WmT[(s*128 + c)*128 + t] = f2b(Wl[(size_t)t*128 + c]);
    }
  } else {
    int col = b - 256;
    const float* Ws; int c; int stride;
    if (col < 384)       { Ws = Wq;  c = col;        stride = 384; }
    else if (col < 768)  { Ws = Wk;  c = col - 384;  stride = 384; }
    else if (col < 1152) { Ws = Wv;  c = col - 768;  stride = 384; }
    else if (col < 1440) { Ws = Wqp; c = col - 1152; stride = 288; }
    else if (col < 1728) { Ws = Wkp; c = col - 1440; stride = 288; }
    else                 { Ws = Wvp; c = col - 1728; stride = 288; }
    if (t < 128) WprojT[(size_t)col*128 + t] = f2b(Ws[(size_t)t*stride + c]);
  }
}

// ---------------- K2: fused attention, XCD-swizzled, all-lane softmax ----------------
#define LGP(i,j,h) ((i)*416 + (j)*13 + (h))
__global__ void __launch_bounds__(512,2) k_attn(
  const float* __restrict__ pf, const unsigned short* __restrict__ Arow,
  const unsigned short* __restrict__ Bvec, const unsigned short* __restrict__ Vcat,
  const unsigned short* __restrict__ WpbT,
  const float* __restrict__ R, const float* __restrict__ coord,
  unsigned short* __restrict__ featb)
{
  extern __shared__ char smem_raw[];
  unsigned short* pftile = (unsigned short*)smem_raw;
  unsigned short* W1 = (unsigned short*)(smem_raw + 81920);
  unsigned short* W2 = (unsigned short*)(smem_raw + 90240);
  float* lgP   = (float*)(smem_raw + 100480);
  float* sden  = lgP;
  float* aggr  = (float*)smem_raw;

  int b = (blockIdx.x & 7) * 32 + (blockIdx.x >> 3);
  int ib = b & 63; int n = b >> 6;
  int i0 = ib * 8;
  int t = threadIdx.x; int w = t >> 6; int l = t & 63;
  int l15 = l & 15, lg4 = l >> 4;

  for (int idx = t; idx < 4640; idx += 512) ((unsigned*)W1)[idx] = 0u;

  if (w >= 4) {
    // ================= LOADER waves =================
    int lw = w - 4;
    bf16x8 aPV[2];
    #pragma unroll
    for (int ks=0; ks<2; ++ks)
      aPV[ks] = *(const bf16x8*)&WpbT[l15*64 + ks*32 + lg4*8];

    float4 rbuf[16];
    #pragma unroll
    for (int pp=0; pp<4; ++pp) {
      int p = 4*lw + pp; int ii = p >> 1; int jloc = (p & 1)*16 + l15;
      const float* src = pf + ((size_t)(n*LL + i0 + ii)*LL + jloc)*CC + lg4*8;
      #pragma unroll
      for (int ks=0; ks<2; ++ks) {
        rbuf[pp*4+ks*2  ] = *(const float4*)(src + ks*32);
        rbuf[pp*4+ks*2+1] = *(const float4*)(src + ks*32 + 4);
      }
    }
    #pragma unroll
    for (int pp=0; pp<4; ++pp) {
      int p = 4*lw + pp; int ii = p >> 1; int jloc = (p & 1)*16 + l15;
      f32x4 cpv = (f32x4){0.f,0.f,0.f,0.f};
      #pragma unroll
      for (int ks=0; ks<2; ++ks) {
        float4 va = rbuf[pp*4+ks*2], vb = rbuf[pp*4+ks*2+1];
        bf16x8 bb;
        bb[0]=(short)f2b(va.x); bb[1]=(short)f2b(va.y); bb[2]=(short)f2b(va.z); bb[3]=(short)f2b(va.w);
        bb[4]=(short)f2b(vb.x); bb[5]=(short)f2b(vb.y); bb[6]=(short)f2b(vb.z); bb[7]=(short)f2b(vb.w);
        cpv = __builtin_amdgcn_mfma_f32_16x16x32_bf16(aPV[ks], bb, cpv, 0,0,0);
        int cbase = ks*32 + lg4*8;
        #pragma unroll
        for (int e=0;e<8;++e) pftile[ii*2560 + (cbase+e)*40 + jloc] = (unsigned short)bb[e];
      }
      #pragma unroll
      for (int r=0;r<4;++r) { int h2 = lg4*4 + r; if (h2 < HH) lgP[LGP(ii, jloc, h2)] = cpv[r]; }
    }
    BAR();
    for (int jt = 0; jt < 16; ++jt) {
      if (jt < 15) {
        int j0s = (jt+1)*32;
        #pragma unroll
        for (int pp=0; pp<4; ++pp) {
          int p = 4*lw + pp; int ii = p >> 1; int jloc = (p & 1)*16 + l15;
          const float* src = pf + ((size_t)(n*LL + i0 + ii)*LL + (j0s + jloc))*CC + lg4*8;
          #pragma unroll
          for (int ks=0; ks<2; ++ks) {
            rbuf[pp*4+ks*2  ] = *(const float4*)(src + ks*32);
            rbuf[pp*4+ks*2+1] = *(const float4*)(src + ks*32 + 4);
          }
        }
      }
      BAR();                               // b1
      if (jt < 15) {
        int buf = (jt+1)&1;
        unsigned short* pft = pftile + buf*20480;
        float* lgPb = lgP + buf*3328;
        #pragma unroll
        for (int pp=0; pp<4; ++pp) {
          int p = 4*lw + pp; int ii = p >> 1; int jloc = (p & 1)*16 + l15;
          f32x4 cpv = (f32x4){0.f,0.f,0.f,0.f};
          #pragma unroll
          for (int ks=0; ks<2; ++ks) {
            float4 va = rbuf[pp*4+ks*2], vb = rbuf[pp*4+ks*2+1];
            bf16x8 bb;
            bb[0]=(short)f2b(va.x); bb[1]=(short)f2b(va.y); bb[2]=(short)f2b(va.z); bb[3]=(short)f2b(va.w);
            bb[4]=(short)f2b(vb.x); bb[5]=(short)f2b(vb.y); bb[6]=(short)f2b(vb.z); bb[7]=(short)f2b(vb.w);
            cpv = __builtin_amdgcn_mfma_f32_16x16x32_bf16(aPV[ks], bb, cpv, 0,0,0);
            int cbase = ks*32 + lg4*8;
            #pragma unroll
            for (int e=0;e<8;++e) pft[ii*2560 + (cbase+e)*40 + jloc] = (unsigned short)bb[e];
          }
          #pragma unroll
          for (int r=0;r<4;++r) { int h2 = lg4*4 + r; if (h2 < HH) lgPb[LGP(ii, jloc, h2)] = cpv[r]; }
        }
      }
      BAR();                               // b2
    }
    BAR();                                 // B_e1
  } else {
    // ================= COMPUTE waves =================
    bf16x8 zz;
    #pragma unroll
    for (int e=0;e<8;++e) zz[e] = 0;
    bf16x8 aAB[3][2];
    #pragma unroll
    for (int hh=0; hh<3; ++hh) {
      int h = 3*w + hh;
      #pragma unroll
      for (int ks=0; ks<2; ++ks)
        aAB[hh][ks] = (l15 < 8) ? *(const bf16x8*)&Arow[(size_t)(n*LL + i0 + l15)*768 + h*64 + ks*32 + lg4*8] : zz;
    }
    f32x4 cNV[3][4]; f32x4 cP[2][4];
    #pragma unroll
    for (int a=0;a<3;++a)
      #pragma unroll
      for (int nt=0;nt<4;++nt) cNV[a][nt] = (f32x4){0.f,0.f,0.f,0.f};
    #pragma unroll
    for (int a=0;a<2;++a)
      #pragma unroll
      for (int nt=0;nt<4;++nt) cP[a][nt] = (f32x4){0.f,0.f,0.f,0.f};
    float s_acc[3][4];
    #pragma unroll
    for (int a=0;a<3;++a)
      #pragma unroll
      for (int r=0;r<4;++r) s_acc[a][r] = 0.f;

    int jh2 = (lg4 >= 2);           // which j-half this lane softmaxes
    int ig  = (lg4 & 1) * 4;        // i-base for this lane's softmax rows

    BAR();
    for (int jt = 0; jt < 16; ++jt) {
      int j0 = jt*32; int cur = jt & 1;
      unsigned short* pft = pftile + cur*20480;
      float* lgPb = lgP + cur*3328;
      f32x4 cL[3][2];
      #pragma unroll
      for (int hh=0; hh<3; ++hh) {
        int h = 3*w + hh;
        cL[hh][0] = (f32x4){0.f,0.f,0.f,0.f};
        cL[hh][1] = (f32x4){0.f,0.f,0.f,0.f};
        #pragma unroll
        for (int ks=0; ks<2; ++ks) {
          bf16x8 b0 = *(const bf16x8*)&Bvec[(size_t)(n*LL + j0 + l15)*768 + h*64 + ks*32 + lg4*8];
          bf16x8 b1 = *(const bf16x8*)&Bvec[(size_t)(n*LL + j0 + 16 + l15)*768 + h*64 + ks*32 + lg4*8];
          cL[hh][0] = __builtin_amdgcn_mfma_f32_16x16x32_bf16(aAB[hh][ks], b0, cL[hh][0], 0,0,0);
          cL[hh][1] = __builtin_amdgcn_mfma_f32_16x16x32_bf16(aAB[hh][ks], b1, cL[hh][1], 0,0,0);
        }
      }
      // ---- SM: all 64 lanes. Upper half-wave takes jh2=1 logits from lower partner. ----
      #pragma unroll
      for (int hh=0; hh<3; ++hh) {
        int h = 3*w + hh;
        #pragma unroll
        for (int r=0;r<4;++r) {
          float other = __shfl_xor(cL[hh][1][r], 32);
          float mine  = (lg4 < 2) ? cL[hh][0][r] : other;
          int i = ig + r;
          int j = jh2*16 + l15;
          float lv = mine + lgPb[LGP(i, j, h)];
          float e = __expf(lv);
          s_acc[hh][r] += e;
          unsigned short eb = f2b(e);
          W1[(h*8 + i)*40 + j] = eb;
          W2[(i*16 + h)*40 + j] = eb;
        }
      }
      BAR();                               // b1
      #pragma unroll
      for (int hh=0; hh<3; ++hh) {
        int h = 3*w + hh;
        bf16x8 aW = *(const bf16x8*)&W1[(h*8 + l15)*40 + lg4*8];
        #pragma unroll
        for (int nt=0; nt<4; ++nt) {
          bf16x8 bV = *(const bf16x8*)&Vcat[(((size_t)n*12 + h)*64 + nt*16 + l15)*512 + j0 + lg4*8];
          cNV[hh][nt] = __builtin_amdgcn_mfma_f32_16x16x32_bf16(aW, bV, cNV[hh][nt], 0,0,0);
        }
      }
      #pragma unroll
      for (int it=0; it<2; ++it) {
        int ii = 2*w + it;
        bf16x8 aW2 = *(const bf16x8*)&W2[(ii*16 + l15)*40 + lg4*8];
        #pragma unroll
        for (int nt=0; nt<4; ++nt) {
          bf16x8 bP = *(const bf16x8*)&pft[ii*2560 + (nt*16 + l15)*40 + lg4*8];
          cP[it][nt] = __builtin_amdgcn_mfma_f32_16x16x32_bf16(aW2, bP, cP[it][nt], 0,0,0);
        }
      }
      BAR();                               // b2
    }
    // ---- epilogue: s reduction (over l15 lanes, then jh2 halves) ----
    #pragma unroll
    for (int hh=0; hh<3; ++hh) {
      int h = 3*w + hh;
      #pragma unroll
      for (int r=0;r<4;++r) {
        float val = s_acc[hh][r];
        #pragma unroll
        for (int o=1;o<16;o<<=1) val += __shfl_xor(val, o);
        val += __shfl_xor(val, 32);
        if (lg4 < 2 && l15 == 0) sden[(lg4*4 + r)*12 + h] = 1.0f / val;
      }
    }
    BAR();                                 // B_e1
    #pragma unroll
    for (int it=0; it<2; ++it) {
      int ii = 2*w + it;
      size_t fb = (size_t)(n*LL + i0 + ii)*DIN;
      #pragma unroll
      for (int nt=0; nt<4; ++nt)
        #pragma unroll
        for (int r=0;r<4;++r) {
          int h2 = lg4*4 + r;
          if (h2 < HH) featb[fb + h2*64 + nt*16 + l15] = f2b(cP[it][nt][r] * sden[ii*12 + h2]);
        }
    }
    if (lg4 < 2) {
      #pragma unroll
      for (int hh=0; hh<3; ++hh) {
        int h = 3*w + hh;
        #pragma unroll
        for (int r=0;r<4;++r) {
          int i = lg4*4 + r;
          float sd = sden[i*12 + h];
          size_t fb = (size_t)(n*LL + i0 + i)*DIN;
          #pragma unroll
          for (int nt=0; nt<2; ++nt)
            featb[fb + 768 + h*32 + nt*16 + l15] = f2b(cNV[hh][nt][r] * sd);
          #pragma unroll
          for (int nt=2; nt<4; ++nt) {
            int d = nt*16 + l15 - 32;
            if (d < 24) aggr[(i*12 + h)*24 + d] = cNV[hh][nt][r] * sd;
          }
        }
      }
    }
  }
  BAR();                                   // B_e2
  for (int idx = t; idx < 768; idx += 512) {
    int i = idx / 96; int rem = idx % 96; int h = rem >> 3; int p = rem & 7;
    int row = n*LL + i0 + i;
    const float* Rl = &R[(size_t)row*9];
    float X0 = aggr[(i*12 + h)*24 + p*3 + 0] - coord[(size_t)row*3 + 0];
    float X1 = aggr[(i*12 + h)*24 + p*3 + 1] - coord[(size_t)row*3 + 1];
    float X2 = aggr[(i*12 + h)*24 + p*3 + 2] - coord[(size_t)row*3 + 2];
    float p0 = Rl[0]*X0 + Rl[3]*X1 + Rl[6]*X2;
    float p1 = Rl[1]*X0 + Rl[4]*X1 + Rl[7]*X2;
    float p2 = Rl[2]*X0 + Rl[5]*X1 + Rl[8]*X2;
    float dist = sqrtf(p0*p0 + p1*p1 + p2*p2);
    float inv = 1.0f / (dist + 1e-4f);
    size_t fb = (size_t)row * DIN;
    int m = h*8 + p;
    featb[fb + 1152 + m*3 + 0] = f2b(p0);
    featb[fb + 1152 + m*3 + 1] = f2b(p1);
    featb[fb + 1152 + m*3 + 2] = f2b(p2);
    featb[fb + 1440 + m] = f2b(dist);
    featb[fb + 1536 + m*3 + 0] = f2b(p0*inv);
    featb[fb + 1536 + m*3 + 1] = f2b(p1*inv);
    featb[fb + 1536 + m*3 + 2] = f2b(p2*inv);
  }
}

// ---------------- K4: fused outproj + LN1 + MLP + LN2 (4-acc ILP) ----------------
__global__ __launch_bounds__(256) void k_head(
  const unsigned short* __restrict__ featb, const float* __restrict__ x,
  const unsigned short* __restrict__ WoutT, const float* __restrict__ bout,
  const float* __restrict__ g1, const float* __restrict__ b1,
  const unsigned short* __restrict__ WmT,
  const float* __restrict__ bm1, const float* __restrict__ bm2, const float* __restrict__ bm3,
  const float* __restrict__ g2, const float* __restrict__ b2,
  float* __restrict__ out)
{
  __shared__ float ybuf[8*128];
  __shared__ float x1f[8*128];
  __shared__ unsigned short x1b[8*136];
  __shared__ unsigned short hbA[8*136];
  __shared__ unsigned short hbB[8*136];
  int row0 = blockIdx.x * 8;
  int t = threadIdx.x; int w = t >> 6; int l = t & 63;
  int l15 = l & 15, lg4 = l >> 4;

  f32x4 acc0a = (f32x4){0.f,0.f,0.f,0.f}, acc1a = (f32x4){0.f,0.f,0.f,0.f};
  f32x4 acc0b = (f32x4){0.f,0.f,0.f,0.f}, acc1b = (f32x4){0.f,0.f,0.f,0.f};
  const unsigned short* ap  = featb + (size_t)(row0 + (l15 & 7))*DIN + lg4*8;
  const unsigned short* bp0 = WoutT + (size_t)(w*32 + l15)*DIN + lg4*8;
  const unsigned short* bp1 = bp0 + 16*DIN;
  for (int ks = 0; ks < 28; ++ks) {
    bf16x8 aA  = *(const bf16x8*)(ap  + ks*32);
    bf16x8 aB  = *(const bf16x8*)(ap  + (28+ks)*32);
    bf16x8 b0A = *(const bf16x8*)(bp0 + ks*32);
    bf16x8 b0B = *(const bf16x8*)(bp0 + (28+ks)*32);
    bf16x8 b1A = *(const bf16x8*)(bp1 + ks*32);
    bf16x8 b1B = *(const bf16x8*)(bp1 + (28+ks)*32);
    acc0a = __builtin_amdgcn_mfma_f32_16x16x32_bf16(aA, b0A, acc0a, 0,0,0);
    acc0b = __builtin_amdgcn_mfma_f32_16x16x32_bf16(aB, b0B, acc0b, 0,0,0);
    acc1a = __builtin_amdgcn_mfma_f32_16x16x32_bf16(aA, b1A, acc1a, 0,0,0);
    acc1b = __builtin_amdgcn_mfma_f32_16x16x32_bf16(aB, b1B, acc1b, 0,0,0);
  }
  {
    bf16x8 aA  = *(const bf16x8*)(ap  + 56*32);
    bf16x8 b0A = *(const bf16x8*)(bp0 + 56*32);
    bf16x8 b1A = *(const bf16x8*)(bp1 + 56*32);
    acc0a = __builtin_amdgcn_mfma_f32_16x16x32_bf16(aA, b0A, acc0a, 0,0,0);
    acc1a = __builtin_amdgcn_mfma_f32_16x16x32_bf16(aA, b1A, acc1a, 0,0,0);
  }
  f32x4 acc0, acc1;
  #pragma unroll
  for (int r=0;r<4;++r) { acc0[r] = acc0a[r] + acc0b[r]; acc1[r] = acc1a[r] + acc1b[r]; }
  #pragma unroll
  for (int r=0;r<4;++r) {
    int m = lg4*4 + r;
    if (m < 8) {
      ybuf[m*128 + w*32 + l15]      = acc0[r];
      ybuf[m*128 + w*32 + 16 + l15] = acc1[r];
    }
  }
  __syncthreads();

  int row = t >> 5, j = t & 31; int grow = row0 + row;
  {
    float y[4];
    #pragma unroll
    for (int c4=0;c4<4;++c4) {
      int c = j + c4*32;
      y[c4] = ybuf[row*128 + c] + x[(size_t)grow*128 + c] + bout[c];
    }
    float sum = y[0]+y[1]+y[2]+y[3];
    #pragma unroll
    for (int o=1;o<32;o<<=1) sum += __shfl_xor(sum, o);
    float mean = sum * (1.0f/128.0f);
    float vs = 0.f;
    #pragma unroll
    for (int c4=0;c4<4;++c4){ y[c4] -= mean; vs += y[c4]*y[c4]; }
    #pragma unroll
    for (int o=1;o<32;o<<=1) vs += __shfl_xor(vs, o);
    float rstd = rsqrtf(vs*(1.0f/128.0f) + 1e-5f);
    #pragma unroll
    for (int c4=0;c4<4;++c4) {
      int c = j + c4*32;
      float xv = y[c4]*rstd*g1[c] + b1[c];
      x1f[row*128 + c] = xv;
      x1b[row*136 + c] = f2b(xv);
    }
  }
  __syncthreads();

  #pragma unroll
  for (int s=0; s<3; ++s) {
    const unsigned short* Ab = (s==0)? x1b : ((s==1)? hbA : hbB);
    const float* bm = (s==0)? bm1 : ((s==1)? bm2 : bm3);
    const unsigned short* Wl = WmT + s*16384;
    f32x4 a0 = (f32x4){0.f,0.f,0.f,0.f}, a1 = (f32x4){0.f,0.f,0.f,0.f};
    #pragma unroll
    for (int ks=0; ks<4; ++ks) {
      bf16x8 a = *(const bf16x8*)&Ab[(l15 & 7)*136 + ks*32 + lg4*8];
      bf16x8 b0 = *(const bf16x8*)&Wl[(size_t)(w*32 + l15)*128 + ks*32 + lg4*8];
      bf16x8 b1v = *(const bf16x8*)&Wl[(size_t)(w*32 + 16 + l15)*128 + ks*32 + lg4*8];
      a0 = __builtin_amdgcn_mfma_f32_16x16x32_bf16(a, b0, a0, 0,0,0);
      a1 = __builtin_amdgcn_mfma_f32_16x16x32_bf16(a, b1v, a1, 0,0,0);
    }
    unsigned short* Nb = (s==0)? hbA : hbB;
    #pragma unroll
    for (int r=0;r<4;++r) {
      int m = lg4*4 + r;
      if (m < 8) {
        int c0 = w*32 + l15, c1 = w*32 + 16 + l15;
        float y0 = a0[r] + bm[c0];
        float y1 = a1[r] + bm[c1];
        if (s < 2) {
          Nb[m*136 + c0] = f2b(fmaxf(y0, 0.f));
          Nb[m*136 + c1] = f2b(fmaxf(y1, 0.f));
        } else {
          ybuf[m*128 + c0] = y0;
          ybuf[m*128 + c1] = y1;
        }
      }
    }
    __syncthreads();
  }

  {
    float y[4];
    #pragma unroll
    for (int c4=0;c4<4;++c4) {
      int c = j + c4*32;
      y[c4] = x1f[row*128 + c] + ybuf[row*128 + c];
    }
    float sum = y[0]+y[1]+y[2]+y[3];
    #pragma unroll
    for (int o=1;o<32;o<<=1) sum += __shfl_xor(sum, o);
    float mean = sum * (1.0f/128.0f);
    float vs = 0.f;
    #pragma unroll
    for (int c4=0;c4<4;++c4){ y[c4] -= mean; vs += y[c4]*y[c4]; }
    #pragma unroll
    for (int o=1;o<32;o<<=1) vs += __shfl_xor(vs, o);
    float rstd = rsqrtf(vs*(1.0f/128.0f) + 1e-5f);
    #pragma unroll
    for (int c4=0;c4<4;++c4) {
      int c = j + c4*32;
      out[(size_t)grow*128 + c] = y[c4]*rstd*g2[c] + b2[c];
    }
  }
}

extern "C" void kernel_launch(void* const* d_in, const int* in_sizes, int n_in,
                              void* d_out, int out_size, void* d_ws, size_t ws_size,
                              hipStream_t stream) {
  const float* R     = (const float*)d_in[0];
  const float* coord = (const float*)d_in[1];
  const float* x     = (const float*)d_in[2];
  const float* pf    = (const float*)d_in[3];
  const float* Wq    = (const float*)d_in[5];
  const float* Wk    = (const float*)d_in[6];
  const float* Wv    = (const float*)d_in[7];
  const float* Wpb   = (const float*)d_in[8];
  const float* sc    = (const float*)d_in[9];
  const float* Wqp   = (const float*)d_in[10];
  const float* Wkp   = (const float*)d_in[11];
  const float* Wvp   = (const float*)d_in[12];
  const float* Wout  = (const float*)d_in[13];
  const float* bout  = (const float*)d_in[14];
  const float* Wm1   = (const float*)d_in[15];
  const float* bm1   = (const float*)d_in[16];
  const float* Wm2   = (const float*)d_in[17];
  const float* bm2   = (const float*)d_in[18];
  const float* Wm3   = (const float*)d_in[19];
  const float* bm3   = (const float*)d_in[20];
  const float* g1    = (const float*)d_in[21];
  const float* b1    = (const float*)d_in[22];
  const float* g2    = (const float*)d_in[23];
  const float* b2    = (const float*)d_in[24];

  float* ws = (float*)d_ws;
  unsigned short* yraw = (unsigned short*)ws;          // 2048*2016 bf16
  float* after    = ws + 2064384;
  unsigned short* Arow = (unsigned short*)after;
  unsigned short* Bvec = (unsigned short*)(after + 786432);
  unsigned short* Vcat = (unsigned short*)(after + 1572864);
  unsigned short* WpbT = (unsigned short*)(after + 2359296);
  unsigned short* featb = (unsigned short*)(after + 2384384);
  unsigned short* WoutT = (unsigned short*)(after + 2384384 + 1867776);
  unsigned short* WmT   = (unsigned short*)(after + 2384384 + 1867776 + 116736);
  unsigned short* WprojT= (unsigned short*)(after + 2384384 + 1867776 + 116736 + 24576);
  float* out      = (float*)d_out;

  k_packW<<<dim3(2272), dim3(256), 0, stream>>>(Wout,Wm1,Wm2,Wm3,Wq,Wk,Wv,Wqp,Wkp,Wvp,WoutT,WmT,WprojT);
  k_projm<<<dim3(256), dim3(256), 0, stream>>>(x, WprojT, yraw);
  k_pack2<<<dim3(NROW/8), dim3(256), 0, stream>>>(yraw,R,coord,sc,Wpb,Arow,Bvec,Vcat,WpbT);
  hipFuncSetAttribute((const void*)k_attn, hipFuncAttributeMaxDynamicSharedMemorySize, 127104);
  k_attn<<<dim3(256), dim3(512), 127104, stream>>>(pf, Arow, Bvec, Vcat, WpbT, R, coord, featb);
  k_head<<<dim3(NROW/8), dim3(256), 0, stream>>>(featb, x, WoutT, bout, g1, b1, WmT, bm1, bm2, bm3, g2, b2, out);
}